// Round 9
// baseline (397.333 us; speedup 1.0000x reference)
//
#include <hip/hip_runtime.h>
#include <hip/hip_bf16.h>

#define BWIN 256
#define NTOK 343
#define CDIM 192
#define NH   6
#define HD   32
#define QKVF 576
#define NROWS (BWIN * NTOK)          // 87808
#define SCALE 0.17677669529663687f   // 1/sqrt(32)
#define LOG2E 1.4426950408889634f

typedef unsigned short u16;
typedef unsigned int   u32;
typedef short bf16x8 __attribute__((ext_vector_type(8)));
typedef float f32x4 __attribute__((ext_vector_type(4)));
typedef unsigned short u16x8 __attribute__((ext_vector_type(8)));

// ws layout (bytes). Interleaved qkvb [row][576] (R0 layout — the 6 head-
// blocks per window share cache lines on the same XCD; load-bearing for
// FETCH). wqb+bqs alias the opb head: dead after gemm_qkv, before attn
// writes opb. All three small tables are in MFMA-fragment order.
#define OFF_QKVB 0UL                 // u16 [87808][576] = 101,154,816
#define OFF_OPB  101154816UL         // u16 [87808][192] =  33,718,272
#define OFF_WQB  101154816UL         // u16 [36][6][64][8] = 221,184 (aliases opb)
#define OFF_BQS  101376000UL         // f32 [576] (aliases opb)
#define OFF_BMB  134873088UL         // u16 [6][22][11][64][8] = 1,486,848
#define OFF_WPB  136359936UL         // u16 [12][6][64][8] = 73,728
#define WS_NEED  136433664UL

__device__ __forceinline__ u16 f2bf(float f) {
    u32 u = __float_as_uint(f);
    u += 0x7FFFu + ((u >> 16) & 1u);           // RNE
    return (u16)(u >> 16);
}
__device__ __forceinline__ float bf2f(u16 h) {
    return __uint_as_float(((u32)h) << 16);
}
__device__ __forceinline__ u32 pk2bf(float a, float b) {
    union { __hip_bfloat162 h; u32 u; } v;
    v.h = __float22bfloat162_rn(make_float2(a, b));   // lo=a, hi=b
    return v.u;
}

__global__ void ws_too_small_sentinel(float* out) { out[0] = 1.0e6f; }

// ---------------------------------------------------------------- small converts
// Frag-order tables. W (both): [fb][kk][lane][8] where lane=(g<<4)|cl holds
// W[fb*16+cl][kk*32+g*8+e] — one coalesced bf16x8/lane B-fragment load.
// Bias: [h][qt(22)][jc(11)][lane][8], e<4 -> j=jc*32+g*4+e, e>=4 ->
// j=jc*32+16+g*4+(e-4); q=qt*16+cl clamped (pad outputs discarded);
// j>=343 = -10000 (validated in R5/R6).
__global__ __launch_bounds__(256) void cvt_small(
    const float* __restrict__ wq, const float* __restrict__ wp,
    const float* __restrict__ bq, const float* __restrict__ btab,
    const int* __restrict__ ridx,
    u16* __restrict__ wqb, u16* __restrict__ wpb,
    float* __restrict__ bqs, u16* __restrict__ bmb)
{
    const int i = blockIdx.x * 256 + threadIdx.x;
    if (i < 110592) {                                 // w_qkv -> frag order
        const int fb = i / 3072;                      // 6*512
        const int r1 = i - fb * 3072;
        const int kk = r1 >> 9;
        const int t  = r1 & 511;
        const int lane = t >> 3, e = t & 7;
        const int row = fb * 16 + (lane & 15);
        const int k   = kk * 32 + (lane >> 4) * 8 + e;
        wqb[i] = f2bf(wq[row * 192 + k] * (row < CDIM ? SCALE * LOG2E : 1.0f));
    } else if (i < 147456) {                          // w_proj -> frag order
        const int u = i - 110592;
        const int fb = u / 3072;
        const int r1 = u - fb * 3072;
        const int kk = r1 >> 9;
        const int t  = r1 & 511;
        const int lane = t >> 3, e = t & 7;
        const int row = fb * 16 + (lane & 15);
        const int k   = kk * 32 + (lane >> 4) * 8 + e;
        wpb[u] = f2bf(wp[row * 192 + k]);
    } else if (i < 148032) {
        const int f = i - 147456;
        bqs[f] = bq[f] * (f < CDIM ? SCALE * LOG2E : 1.0f);
    } else if (i < 891456) {                          // frag-order bias
        const int u = i - 148032;                     // [0, 743424)
        const int hh = u / 123904;                    // 22*11*512
        const int rem = u - hh * 123904;
        const int qt = rem / 5632;                    // 11*512
        const int rem2 = rem - qt * 5632;
        const int jc = rem2 >> 9;
        const int t = rem2 & 511;
        const int lane = t >> 3, e = t & 7;
        const int cl = lane & 15, g = lane >> 4;
        const int q = min(qt * 16 + cl, NTOK - 1);
        const int j = jc * 32 + ((e < 4) ? (g * 4 + e) : (16 + g * 4 + (e - 4)));
        const float v = (j < NTOK) ? btab[ridx[q * NTOK + j] * NH + hh] * LOG2E
                                   : -10000.0f;
        bmb[u] = f2bf(v);
    }
}

// ---------------------------------------------------------------- qkv GEMM
// R8-verbatim: single X read (64-row tile staged once, loop 6 f-chunks),
// W frags coalesced frag-order, 4 blocks/CU.
__global__ __launch_bounds__(256, 4) void gemm_qkv(
    const float* __restrict__ x, const u16* __restrict__ wqb,
    const float* __restrict__ bqs, u16* __restrict__ qkvb)
{
    __shared__ __align__(16) u16 Xs[64 * 200];        // X tile, live whole kernel
    __shared__ __align__(16) u16 Ct[64 * 104];        // epilogue transpose buffer
    const int m0 = blockIdx.x * 64;
    const int tid = threadIdx.x;
    const int wave = tid >> 6, lane = tid & 63, g = lane >> 4, cl = lane & 15;
    const int wm = (wave >> 1) * 32, wf = (wave & 1) * 48;

    #pragma unroll
    for (int p = 0; p < 12; ++p) {
        const int u = tid + 256 * p;
        const int row = u / 48, c = u - row * 48;
        const float4 v = *(const float4*)(x + (size_t)(m0 + row) * CDIM + c * 4);
        *(uint2*)(Xs + row * 200 + c * 4) = make_uint2(pk2bf(v.x, v.y), pk2bf(v.z, v.w));
    }
    __syncthreads();

    for (int fc = 0; fc < 6; ++fc) {
        const int f0 = fc * 96;
        f32x4 acc[2][3];
        #pragma unroll
        for (int t = 0; t < 2; ++t)
            #pragma unroll
            for (int s = 0; s < 3; ++s) acc[t][s] = (f32x4){0.f, 0.f, 0.f, 0.f};

        const u16* wbase = wqb + (size_t)(fc * 6 + (wave & 1) * 3) * 3072 + lane * 8;
        #pragma unroll
        for (int kk = 0; kk < 6; ++kk) {
            const int kcol = kk * 32;
            bf16x8 a[2], bb[3];
            #pragma unroll
            for (int s = 0; s < 3; ++s)
                bb[s] = *(const bf16x8*)(wbase + s * 3072 + kk * 512);
            #pragma unroll
            for (int t = 0; t < 2; ++t)
                a[t] = *(const bf16x8*)(Xs + (wm + t * 16 + cl) * 200 + kcol + g * 8);
            #pragma unroll
            for (int t = 0; t < 2; ++t)
                #pragma unroll
                for (int s = 0; s < 3; ++s)
                    acc[t][s] = __builtin_amdgcn_mfma_f32_16x16x32_bf16(a[t], bb[s], acc[t][s], 0, 0, 0);
        }

        __syncthreads();                              // prev fc's Ct reads done
        #pragma unroll
        for (int s = 0; s < 3; ++s) {
            const float bv = bqs[f0 + wf + s * 16 + cl];
            #pragma unroll
            for (int t = 0; t < 2; ++t) {
                const int row = wm + t * 16 + g * 4;
                const int col = wf + s * 16 + cl;
                const u32 p01 = pk2bf(acc[t][s][0] + bv, acc[t][s][1] + bv);
                const u32 p23 = pk2bf(acc[t][s][2] + bv, acc[t][s][3] + bv);
                Ct[(row + 0) * 104 + col] = (u16)p01;
                Ct[(row + 1) * 104 + col] = (u16)(p01 >> 16);
                Ct[(row + 2) * 104 + col] = (u16)p23;
                Ct[(row + 3) * 104 + col] = (u16)(p23 >> 16);
            }
        }
        __syncthreads();
        #pragma unroll
        for (int p = 0; p < 3; ++p) {                 // coalesced 16B stores
            const int u = tid + 256 * p;
            const int row = u / 12, c = u - row * 12;
            *(float4*)(qkvb + (size_t)(m0 + row) * QKVF + f0 + c * 8) =
                *(const float4*)(Ct + row * 104 + c * 8);
        }
    }
}

// ---------------------------------------------------------------- attention
// R8 structure + 2-deep K/bias prefetch pipeline (named dual register
// buffers, fully-unrolled pair loop -> all indices compile-time). Loads for
// jc+2 issue at jc: ~2 bodies of latency cover for the 16-line K gather.
#define LDK(ROW) (*(const bf16x8*)(qkvb + (rowbase + min(ROW, NTOK - 1)) * QKVF + CDIM + h * HD + g * 8))
#define LDBA(JC) (*(const u16x8*)(bpA + (JC) * 512))
#define LDBB(JC) (*(const u16x8*)(bpB + (JC) * 512))

#define JCBODY(J0, CK0, CK1, CA, CB) do {                                            \
    const bf16x8 vb0 = *(const bf16x8*)&Vt[cl][(J0) + g * 8];                        \
    const bf16x8 vb1 = *(const bf16x8*)&Vt[16 + cl][(J0) + g * 8];                   \
    {                                                                                \
        f32x4 c0 = { bf2f((CA)[0]), bf2f((CA)[1]), bf2f((CA)[2]), bf2f((CA)[3]) };   \
        f32x4 c1 = { bf2f((CA)[4]), bf2f((CA)[5]), bf2f((CA)[6]), bf2f((CA)[7]) };   \
        const f32x4 s0 = __builtin_amdgcn_mfma_f32_16x16x32_bf16(CK0, qa0, c0, 0, 0, 0); \
        const f32x4 s1 = __builtin_amdgcn_mfma_f32_16x16x32_bf16(CK1, qa0, c1, 0, 0, 0); \
        union { bf16x8 v; u32 w[4]; } pa;                                            \
        pa.w[0] = pk2bf(__builtin_amdgcn_exp2f(s0[0]), __builtin_amdgcn_exp2f(s0[1])); \
        pa.w[1] = pk2bf(__builtin_amdgcn_exp2f(s0[2]), __builtin_amdgcn_exp2f(s0[3])); \
        pa.w[2] = pk2bf(__builtin_amdgcn_exp2f(s1[0]), __builtin_amdgcn_exp2f(s1[1])); \
        pa.w[3] = pk2bf(__builtin_amdgcn_exp2f(s1[2]), __builtin_amdgcn_exp2f(s1[3])); \
        oA0 = __builtin_amdgcn_mfma_f32_16x16x32_bf16(pa.v, vb0, oA0, 0, 0, 0);      \
        oA1 = __builtin_amdgcn_mfma_f32_16x16x32_bf16(pa.v, vb1, oA1, 0, 0, 0);      \
        lA  = __builtin_amdgcn_mfma_f32_16x16x32_bf16(pa.v, ones, lA, 0, 0, 0);      \
    }                                                                                \
    {                                                                                \
        f32x4 c0 = { bf2f((CB)[0]), bf2f((CB)[1]), bf2f((CB)[2]), bf2f((CB)[3]) };   \
        f32x4 c1 = { bf2f((CB)[4]), bf2f((CB)[5]), bf2f((CB)[6]), bf2f((CB)[7]) };   \
        const f32x4 s0 = __builtin_amdgcn_mfma_f32_16x16x32_bf16(CK0, qa1, c0, 0, 0, 0); \
        const f32x4 s1 = __builtin_amdgcn_mfma_f32_16x16x32_bf16(CK1, qa1, c1, 0, 0, 0); \
        union { bf16x8 v; u32 w[4]; } pa;                                            \
        pa.w[0] = pk2bf(__builtin_amdgcn_exp2f(s0[0]), __builtin_amdgcn_exp2f(s0[1])); \
        pa.w[1] = pk2bf(__builtin_amdgcn_exp2f(s0[2]), __builtin_amdgcn_exp2f(s0[3])); \
        pa.w[2] = pk2bf(__builtin_amdgcn_exp2f(s1[0]), __builtin_amdgcn_exp2f(s1[1])); \
        pa.w[3] = pk2bf(__builtin_amdgcn_exp2f(s1[2]), __builtin_amdgcn_exp2f(s1[3])); \
        oB0 = __builtin_amdgcn_mfma_f32_16x16x32_bf16(pa.v, vb0, oB0, 0, 0, 0);      \
        oB1 = __builtin_amdgcn_mfma_f32_16x16x32_bf16(pa.v, vb1, oB1, 0, 0, 0);      \
        lB  = __builtin_amdgcn_mfma_f32_16x16x32_bf16(pa.v, ones, lB, 0, 0, 0);      \
    }                                                                                \
} while (0)

__global__ __launch_bounds__(256, 4) void attn_mfma(
    const u16* __restrict__ qkvb, const u16* __restrict__ bmb,
    u16* __restrict__ opb)
{
    __shared__ u16 Vt[HD][360];      // [d][j-slot] 23040 B
    __shared__ u16 Os[4][16][32];    // per-wave O staging 4096 B
    const int b = blockIdx.x, h = blockIdx.y;
    const int tid = threadIdx.x;
    const int wave = tid >> 6, lane = tid & 63, g = lane >> 4, cl = lane & 15;
    const size_t rowbase = (size_t)b * NTOK;

    for (int u = tid; u < 1408; u += 256) {           // V stage, sigma slots
        const int row = u >> 2, seg = u & 3;
        union { float4 f; u16 hx[8]; } vv;
        vv.f = make_float4(0.f, 0.f, 0.f, 0.f);
        if (row < NTOK)
            vv.f = *(const float4*)(qkvb + (rowbase + row) * QKVF + 2 * CDIM + h * HD + seg * 8);
        const int jl = row & 31;
        const int slot = (jl < 16) ? ((jl >> 2) << 3) + (jl & 3)
                                   : (((jl - 16) >> 2) << 3) + 4 + (jl & 3);
        const int pcol = (row & ~31) + slot;
        #pragma unroll
        for (int e = 0; e < 8; ++e) Vt[seg * 8 + e][pcol] = vv.hx[e];
    }
    __syncthreads();

    bf16x8 ones;
    #pragma unroll
    for (int e = 0; e < 8; ++e) ones[e] = (short)0x3F80;

    for (int base = wave * 2; base < 22; base += 8) { // 11 pairs total
        const int q0a = base * 16, q0b = q0a + 16;
        const bf16x8 qa0 = *(const bf16x8*)(qkvb + (rowbase + min(q0a + cl, NTOK - 1)) * QKVF + h * HD + g * 8);
        const bf16x8 qa1 = *(const bf16x8*)(qkvb + (rowbase + min(q0b + cl, NTOK - 1)) * QKVF + h * HD + g * 8);
        const u16* bpA = bmb + ((size_t)(h * 22 + base) * 11) * 512 + lane * 8;
        const u16* bpB = bpA + 5632;                  // next q-tile (11*512)

        // 2-deep prologue: jc=0 and jc=1 in flight
        bf16x8 k0a = LDK(cl),      k0b = LDK(16 + cl);
        u16x8  b0A = LDBA(0),      b0B = LDBB(0);
        bf16x8 k1a = LDK(32 + cl), k1b = LDK(48 + cl);
        u16x8  b1A = LDBA(1),      b1B = LDBB(1);

        f32x4 oA0 = {0,0,0,0}, oA1 = {0,0,0,0}, lA = {0,0,0,0};
        f32x4 oB0 = {0,0,0,0}, oB1 = {0,0,0,0}, lB = {0,0,0,0};

        #pragma unroll
        for (int p = 0; p < 5; ++p) {
            {   // even jc = 2p: consume buf0, prefetch jc+2 into buf0
                const int jc2 = 2 * p + 2;
                const bf16x8 nka = LDK(jc2 * 32 + cl), nkb = LDK(jc2 * 32 + 16 + cl);
                const u16x8  nA  = LDBA(jc2),          nB  = LDBB(jc2);
                JCBODY(2 * p * 32, k0a, k0b, b0A, b0B);
                k0a = nka; k0b = nkb; b0A = nA; b0B = nB;
            }
            if (2 * p + 3 <= 10) {   // odd jc = 2p+1: consume buf1, prefetch jc+2
                const int jc3 = 2 * p + 3;
                const bf16x8 nka = LDK(jc3 * 32 + cl), nkb = LDK(jc3 * 32 + 16 + cl);
                const u16x8  nA  = LDBA(jc3),          nB  = LDBB(jc3);
                JCBODY((2 * p + 1) * 32, k1a, k1b, b1A, b1B);
                k1a = nka; k1b = nkb; b1A = nA; b1B = nB;
            } else {
                JCBODY((2 * p + 1) * 32, k1a, k1b, b1A, b1B);
            }
        }
        JCBODY(320, k0a, k0b, b0A, b0B);              // jc=10

        #pragma unroll
        for (int half = 0; half < 2; ++half) {
            const f32x4 o0 = half ? oB0 : oA0;
            const f32x4 o1 = half ? oB1 : oA1;
            const f32x4 lc = half ? lB : lA;
            const int q0 = half ? q0b : q0a;
            #pragma unroll
            for (int r = 0; r < 4; ++r) {
                const float inv = 1.0f / lc[r];
                Os[wave][g * 4 + r][cl]      = f2bf(o0[r] * inv);
                Os[wave][g * 4 + r][16 + cl] = f2bf(o1[r] * inv);
            }
            const int row = lane >> 2, cg = (lane & 3) * 8;
            const int q = q0 + row;
            if (q < NTOK)
                *(float4*)(opb + (rowbase + q) * CDIM + h * HD + cg) =
                    *(const float4*)&Os[wave][row][cg];
        }
    }
}

// ---------------------------------------------------------------- proj GEMM
// Single opb read: 64-row tile staged ONCE, loop both 96-col f-chunks
// in-block (was grid-parallel -> 2x opb re-read). One-pass epilogue: 4 waves
// write disjoint Cf regions. LDS 52,224B -> 3 blocks/CU.
__global__ __launch_bounds__(256, 3) void gemm_proj(
    const u16* __restrict__ opb, const u16* __restrict__ wpb,
    const float* __restrict__ bp, float* __restrict__ out)
{
    __shared__ __align__(16) u16 Xs[64 * 200];        // live whole kernel
    __shared__ __align__(16) float Cf[64 * 104];      // epilogue transpose (f32)
    const int m0 = blockIdx.x * 64;
    const int tid = threadIdx.x;
    const int wave = tid >> 6, lane = tid & 63, g = lane >> 4, cl = lane & 15;
    const int wm = (wave >> 1) * 32, wf = (wave & 1) * 48;

    // stage once: 64 rows x 24 float4 units = 1536 (6 passes of 256)
    #pragma unroll
    for (int p = 0; p < 6; ++p) {
        const int u = tid + 256 * p;
        const int row = u / 24, c = u - row * 24;
        *(float4*)(Xs + row * 200 + c * 8) =
            *(const float4*)(opb + (size_t)(m0 + row) * CDIM + c * 8);
    }
    __syncthreads();

    for (int fc = 0; fc < 2; ++fc) {
        const int f0 = fc * 96;
        f32x4 acc[2][3];
        #pragma unroll
        for (int t = 0; t < 2; ++t)
            #pragma unroll
            for (int s = 0; s < 3; ++s) acc[t][s] = (f32x4){0.f, 0.f, 0.f, 0.f};

        const u16* wbase = wpb + (size_t)(fc * 6 + (wave & 1) * 3) * 3072 + lane * 8;
        #pragma unroll
        for (int kk = 0; kk < 6; ++kk) {
            const int kcol = kk * 32;
            bf16x8 a[2], bb[3];
            #pragma unroll
            for (int s = 0; s < 3; ++s)
                bb[s] = *(const bf16x8*)(wbase + s * 3072 + kk * 512);
            #pragma unroll
            for (int t = 0; t < 2; ++t)
                a[t] = *(const bf16x8*)(Xs + (wm + t * 16 + cl) * 200 + kcol + g * 8);
            #pragma unroll
            for (int t = 0; t < 2; ++t)
                #pragma unroll
                for (int s = 0; s < 3; ++s)
                    acc[t][s] = __builtin_amdgcn_mfma_f32_16x16x32_bf16(a[t], bb[s], acc[t][s], 0, 0, 0);
        }

        __syncthreads();                              // prev fc's Cf reads done
        #pragma unroll
        for (int s = 0; s < 3; ++s) {
            const float bv = bp[f0 + wf + s * 16 + cl];
            #pragma unroll
            for (int t = 0; t < 2; ++t)
                #pragma unroll
                for (int r = 0; r < 4; ++r)
                    Cf[(wm + t * 16 + g * 4 + r) * 104 + wf + s * 16 + cl] = acc[t][s][r] + bv;
        }
        __syncthreads();
        #pragma unroll
        for (int p = 0; p < 6; ++p) {                 // coalesced 16B stores
            const int u = tid + 256 * p;
            const int row = u / 24, c = u - row * 24;
            *(float4*)(out + (size_t)(m0 + row) * CDIM + f0 + c * 4) =
                *(const float4*)(Cf + row * 104 + c * 4);
        }
    }
}

// ---------------------------------------------------------------- launch
extern "C" void kernel_launch(void* const* d_in, const int* in_sizes, int n_in,
                              void* d_out, int out_size, void* d_ws, size_t ws_size,
                              hipStream_t stream) {
    const float* x     = (const float*)d_in[0];
    const float* wqkv  = (const float*)d_in[1];
    const float* bqkv  = (const float*)d_in[2];
    const float* wproj = (const float*)d_in[3];
    const float* bproj = (const float*)d_in[4];
    const float* btab  = (const float*)d_in[5];
    const int*   ridx  = (const int*)d_in[6];
    float* out = (float*)d_out;

    if (ws_size < WS_NEED) {
        hipLaunchKernelGGL(ws_too_small_sentinel, dim3(1), dim3(1), 0, stream, out);
        return;
    }
    char* ws = (char*)d_ws;
    u16*   qkvb = (u16*)(ws + OFF_QKVB);
    u16*   wqb  = (u16*)(ws + OFF_WQB);
    u16*   wpb  = (u16*)(ws + OFF_WPB);
    float* bqs  = (float*)(ws + OFF_BQS);
    u16*   bmb  = (u16*)(ws + OFF_BMB);
    u16*   opb  = (u16*)(ws + OFF_OPB);

    hipLaunchKernelGGL(cvt_small, dim3(3483), dim3(256), 0, stream,
                       wqkv, wproj, bqkv, btab, ridx, wqb, wpb, bqs, bmb);
    hipLaunchKernelGGL(gemm_qkv, dim3(NROWS / 64), dim3(256), 0, stream,
                       x, wqb, bqs, qkvb);
    hipLaunchKernelGGL(attn_mfma, dim3(BWIN, NH), dim3(256), 0, stream,
                       qkvb, bmb, opb);
    hipLaunchKernelGGL(gemm_proj, dim3(NROWS / 64), dim3(256), 0, stream,
                       opb, wpb, bproj, out);
}

// Round 10
// 255.001 us; speedup vs baseline: 1.5582x; 1.5582x over previous
//
#include <hip/hip_runtime.h>
#include <hip/hip_bf16.h>

#define BWIN 256
#define NTOK 343
#define CDIM 192
#define NH   6
#define HD   32
#define QKVF 576
#define NROWS (BWIN * NTOK)          // 87808
#define SCALE 0.17677669529663687f   // 1/sqrt(32)
#define LOG2E 1.4426950408889634f

typedef unsigned short u16;
typedef unsigned int   u32;
typedef short bf16x8 __attribute__((ext_vector_type(8)));
typedef float f32x4 __attribute__((ext_vector_type(4)));
typedef unsigned short u16x8 __attribute__((ext_vector_type(8)));

// ws layout (bytes). Interleaved qkvb [row][576] (R0 layout — the 6 head-
// blocks per window share cache lines on the same XCD; load-bearing for
// FETCH). wqb+bqs alias the opb head: dead after gemm_qkv, before attn
// writes opb. All three small tables are in MFMA-fragment order.
#define OFF_QKVB 0UL                 // u16 [87808][576] = 101,154,816
#define OFF_OPB  101154816UL         // u16 [87808][192] =  33,718,272
#define OFF_WQB  101154816UL         // u16 [36][6][64][8] = 221,184 (aliases opb)
#define OFF_BQS  101376000UL         // f32 [576] (aliases opb)
#define OFF_BMB  134873088UL         // u16 [6][22][11][64][8] = 1,486,848
#define OFF_WPB  136359936UL         // u16 [12][6][64][8] = 73,728
#define WS_NEED  136433664UL

__device__ __forceinline__ u16 f2bf(float f) {
    u32 u = __float_as_uint(f);
    u += 0x7FFFu + ((u >> 16) & 1u);           // RNE
    return (u16)(u >> 16);
}
__device__ __forceinline__ float bf2f(u16 h) {
    return __uint_as_float(((u32)h) << 16);
}
__device__ __forceinline__ u32 pk2bf(float a, float b) {
    union { __hip_bfloat162 h; u32 u; } v;
    v.h = __float22bfloat162_rn(make_float2(a, b));   // lo=a, hi=b
    return v.u;
}

__global__ void ws_too_small_sentinel(float* out) { out[0] = 1.0e6f; }

// ---------------------------------------------------------------- small converts
// Frag-order tables. W (both): [fb][kk][lane][8] where lane=(g<<4)|cl holds
// W[fb*16+cl][kk*32+g*8+e] — one coalesced bf16x8/lane B-fragment load.
// Bias: [h][qt(22)][jc(11)][lane][8], e<4 -> j=jc*32+g*4+e, e>=4 ->
// j=jc*32+16+g*4+(e-4); q=qt*16+cl clamped (pad outputs discarded);
// j>=343 = -10000 (validated in R5/R6).
__global__ __launch_bounds__(256) void cvt_small(
    const float* __restrict__ wq, const float* __restrict__ wp,
    const float* __restrict__ bq, const float* __restrict__ btab,
    const int* __restrict__ ridx,
    u16* __restrict__ wqb, u16* __restrict__ wpb,
    float* __restrict__ bqs, u16* __restrict__ bmb)
{
    const int i = blockIdx.x * 256 + threadIdx.x;
    if (i < 110592) {                                 // w_qkv -> frag order
        const int fb = i / 3072;                      // 6*512
        const int r1 = i - fb * 3072;
        const int kk = r1 >> 9;
        const int t  = r1 & 511;
        const int lane = t >> 3, e = t & 7;
        const int row = fb * 16 + (lane & 15);
        const int k   = kk * 32 + (lane >> 4) * 8 + e;
        wqb[i] = f2bf(wq[row * 192 + k] * (row < CDIM ? SCALE * LOG2E : 1.0f));
    } else if (i < 147456) {                          // w_proj -> frag order
        const int u = i - 110592;
        const int fb = u / 3072;
        const int r1 = u - fb * 3072;
        const int kk = r1 >> 9;
        const int t  = r1 & 511;
        const int lane = t >> 3, e = t & 7;
        const int row = fb * 16 + (lane & 15);
        const int k   = kk * 32 + (lane >> 4) * 8 + e;
        wpb[u] = f2bf(wp[row * 192 + k]);
    } else if (i < 148032) {
        const int f = i - 147456;
        bqs[f] = bq[f] * (f < CDIM ? SCALE * LOG2E : 1.0f);
    } else if (i < 891456) {                          // frag-order bias
        const int u = i - 148032;                     // [0, 743424)
        const int hh = u / 123904;                    // 22*11*512
        const int rem = u - hh * 123904;
        const int qt = rem / 5632;                    // 11*512
        const int rem2 = rem - qt * 5632;
        const int jc = rem2 >> 9;
        const int t = rem2 & 511;
        const int lane = t >> 3, e = t & 7;
        const int cl = lane & 15, g = lane >> 4;
        const int q = min(qt * 16 + cl, NTOK - 1);
        const int j = jc * 32 + ((e < 4) ? (g * 4 + e) : (16 + g * 4 + (e - 4)));
        const float v = (j < NTOK) ? btab[ridx[q * NTOK + j] * NH + hh] * LOG2E
                                   : -10000.0f;
        bmb[u] = f2bf(v);
    }
}

// ---------------------------------------------------------------- qkv GEMM
// R8-verbatim: single X read (64-row tile staged once, loop 6 f-chunks),
// W frags coalesced frag-order, 4 blocks/CU.
__global__ __launch_bounds__(256, 4) void gemm_qkv(
    const float* __restrict__ x, const u16* __restrict__ wqb,
    const float* __restrict__ bqs, u16* __restrict__ qkvb)
{
    __shared__ __align__(16) u16 Xs[64 * 200];        // X tile, live whole kernel
    __shared__ __align__(16) u16 Ct[64 * 104];        // epilogue transpose buffer
    const int m0 = blockIdx.x * 64;
    const int tid = threadIdx.x;
    const int wave = tid >> 6, lane = tid & 63, g = lane >> 4, cl = lane & 15;
    const int wm = (wave >> 1) * 32, wf = (wave & 1) * 48;

    #pragma unroll
    for (int p = 0; p < 12; ++p) {
        const int u = tid + 256 * p;
        const int row = u / 48, c = u - row * 48;
        const float4 v = *(const float4*)(x + (size_t)(m0 + row) * CDIM + c * 4);
        *(uint2*)(Xs + row * 200 + c * 4) = make_uint2(pk2bf(v.x, v.y), pk2bf(v.z, v.w));
    }
    __syncthreads();

    for (int fc = 0; fc < 6; ++fc) {
        const int f0 = fc * 96;
        f32x4 acc[2][3];
        #pragma unroll
        for (int t = 0; t < 2; ++t)
            #pragma unroll
            for (int s = 0; s < 3; ++s) acc[t][s] = (f32x4){0.f, 0.f, 0.f, 0.f};

        const u16* wbase = wqb + (size_t)(fc * 6 + (wave & 1) * 3) * 3072 + lane * 8;
        #pragma unroll
        for (int kk = 0; kk < 6; ++kk) {
            const int kcol = kk * 32;
            bf16x8 a[2], bb[3];
            #pragma unroll
            for (int s = 0; s < 3; ++s)
                bb[s] = *(const bf16x8*)(wbase + s * 3072 + kk * 512);
            #pragma unroll
            for (int t = 0; t < 2; ++t)
                a[t] = *(const bf16x8*)(Xs + (wm + t * 16 + cl) * 200 + kcol + g * 8);
            #pragma unroll
            for (int t = 0; t < 2; ++t)
                #pragma unroll
                for (int s = 0; s < 3; ++s)
                    acc[t][s] = __builtin_amdgcn_mfma_f32_16x16x32_bf16(a[t], bb[s], acc[t][s], 0, 0, 0);
        }

        __syncthreads();                              // prev fc's Ct reads done
        #pragma unroll
        for (int s = 0; s < 3; ++s) {
            const float bv = bqs[f0 + wf + s * 16 + cl];
            #pragma unroll
            for (int t = 0; t < 2; ++t) {
                const int row = wm + t * 16 + g * 4;
                const int col = wf + s * 16 + cl;
                const u32 p01 = pk2bf(acc[t][s][0] + bv, acc[t][s][1] + bv);
                const u32 p23 = pk2bf(acc[t][s][2] + bv, acc[t][s][3] + bv);
                Ct[(row + 0) * 104 + col] = (u16)p01;
                Ct[(row + 1) * 104 + col] = (u16)(p01 >> 16);
                Ct[(row + 2) * 104 + col] = (u16)p23;
                Ct[(row + 3) * 104 + col] = (u16)(p23 >> 16);
            }
        }
        __syncthreads();
        #pragma unroll
        for (int p = 0; p < 3; ++p) {                 // coalesced 16B stores
            const int u = tid + 256 * p;
            const int row = u / 12, c = u - row * 12;
            *(float4*)(qkvb + (size_t)(m0 + row) * QKVF + f0 + c * 8) =
                *(const float4*)(Ct + row * 104 + c * 8);
        }
    }
}

// ---------------------------------------------------------------- attention
// R8-verbatim (best measured: 77us). Interleaved layout, clamps, occ 4,
// frag-order coalesced bias, 1-deep just-in-time prefetch. NOTE R9 lesson:
// 2-deep named-buffer pipeline -> VGPR spill -> 550MB scratch traffic, 3x
// slower. Do not deepen per-wave pipelining here.
__global__ __launch_bounds__(256, 4) void attn_mfma(
    const u16* __restrict__ qkvb, const u16* __restrict__ bmb,
    u16* __restrict__ opb)
{
    __shared__ u16 Vt[HD][360];      // [d][j-slot] 23040 B
    __shared__ u16 Os[4][16][32];    // per-wave O staging 4096 B
    const int b = blockIdx.x, h = blockIdx.y;
    const int tid = threadIdx.x;
    const int wave = tid >> 6, lane = tid & 63, g = lane >> 4, cl = lane & 15;
    const size_t rowbase = (size_t)b * NTOK;

    for (int u = tid; u < 1408; u += 256) {           // V stage, sigma slots
        const int row = u >> 2, seg = u & 3;
        union { float4 f; u16 hx[8]; } vv;
        vv.f = make_float4(0.f, 0.f, 0.f, 0.f);
        if (row < NTOK)
            vv.f = *(const float4*)(qkvb + (rowbase + row) * QKVF + 2 * CDIM + h * HD + seg * 8);
        const int jl = row & 31;
        const int slot = (jl < 16) ? ((jl >> 2) << 3) + (jl & 3)
                                   : (((jl - 16) >> 2) << 3) + 4 + (jl & 3);
        const int pcol = (row & ~31) + slot;
        #pragma unroll
        for (int e = 0; e < 8; ++e) Vt[seg * 8 + e][pcol] = vv.hx[e];
    }
    __syncthreads();

    bf16x8 ones;
    #pragma unroll
    for (int e = 0; e < 8; ++e) ones[e] = (short)0x3F80;

    for (int base = wave * 2; base < 22; base += 8) { // 11 pairs total
        const int q0a = base * 16, q0b = q0a + 16;
        const bf16x8 qa0 = *(const bf16x8*)(qkvb + (rowbase + min(q0a + cl, NTOK - 1)) * QKVF + h * HD + g * 8);
        const bf16x8 qa1 = *(const bf16x8*)(qkvb + (rowbase + min(q0b + cl, NTOK - 1)) * QKVF + h * HD + g * 8);
        const u16* bpA = bmb + ((size_t)(h * 22 + base) * 11) * 512 + lane * 8;
        const u16* bpB = bpA + 5632;                  // next q-tile (11*512)

        bf16x8 kb0 = *(const bf16x8*)(qkvb + (rowbase + cl) * QKVF + CDIM + h * HD + g * 8);
        bf16x8 kb1 = *(const bf16x8*)(qkvb + (rowbase + 16 + cl) * QKVF + CDIM + h * HD + g * 8);
        u16x8 bA = *(const u16x8*)(bpA);
        u16x8 bB = *(const u16x8*)(bpB);

        f32x4 oA0 = {0,0,0,0}, oA1 = {0,0,0,0}, lA = {0,0,0,0};
        f32x4 oB0 = {0,0,0,0}, oB1 = {0,0,0,0}, lB = {0,0,0,0};

        for (int jc = 0; jc < 11; ++jc) {
            const int j0 = jc * 32;
            const bf16x8 ck0 = kb0, ck1 = kb1;
            const u16x8 cA = bA, cB = bB;
            if (jc < 10) {
                const int jn = j0 + 32;
                kb0 = *(const bf16x8*)(qkvb + (rowbase + min(jn + cl, NTOK - 1)) * QKVF + CDIM + h * HD + g * 8);
                kb1 = *(const bf16x8*)(qkvb + (rowbase + min(jn + 16 + cl, NTOK - 1)) * QKVF + CDIM + h * HD + g * 8);
                bA = *(const u16x8*)(bpA + (jc + 1) * 512);
                bB = *(const u16x8*)(bpB + (jc + 1) * 512);
            }
            const bf16x8 vb0 = *(const bf16x8*)&Vt[cl][j0 + g * 8];
            const bf16x8 vb1 = *(const bf16x8*)&Vt[16 + cl][j0 + g * 8];

            {
                f32x4 c0 = { bf2f(cA[0]), bf2f(cA[1]), bf2f(cA[2]), bf2f(cA[3]) };
                f32x4 c1 = { bf2f(cA[4]), bf2f(cA[5]), bf2f(cA[6]), bf2f(cA[7]) };
                const f32x4 s0 = __builtin_amdgcn_mfma_f32_16x16x32_bf16(ck0, qa0, c0, 0, 0, 0);
                const f32x4 s1 = __builtin_amdgcn_mfma_f32_16x16x32_bf16(ck1, qa0, c1, 0, 0, 0);
                union { bf16x8 v; u32 w[4]; } pa;
                pa.w[0] = pk2bf(__builtin_amdgcn_exp2f(s0[0]), __builtin_amdgcn_exp2f(s0[1]));
                pa.w[1] = pk2bf(__builtin_amdgcn_exp2f(s0[2]), __builtin_amdgcn_exp2f(s0[3]));
                pa.w[2] = pk2bf(__builtin_amdgcn_exp2f(s1[0]), __builtin_amdgcn_exp2f(s1[1]));
                pa.w[3] = pk2bf(__builtin_amdgcn_exp2f(s1[2]), __builtin_amdgcn_exp2f(s1[3]));
                oA0 = __builtin_amdgcn_mfma_f32_16x16x32_bf16(pa.v, vb0, oA0, 0, 0, 0);
                oA1 = __builtin_amdgcn_mfma_f32_16x16x32_bf16(pa.v, vb1, oA1, 0, 0, 0);
                lA  = __builtin_amdgcn_mfma_f32_16x16x32_bf16(pa.v, ones, lA, 0, 0, 0);
            }
            {
                f32x4 c0 = { bf2f(cB[0]), bf2f(cB[1]), bf2f(cB[2]), bf2f(cB[3]) };
                f32x4 c1 = { bf2f(cB[4]), bf2f(cB[5]), bf2f(cB[6]), bf2f(cB[7]) };
                const f32x4 s0 = __builtin_amdgcn_mfma_f32_16x16x32_bf16(ck0, qa1, c0, 0, 0, 0);
                const f32x4 s1 = __builtin_amdgcn_mfma_f32_16x16x32_bf16(ck1, qa1, c1, 0, 0, 0);
                union { bf16x8 v; u32 w[4]; } pa;
                pa.w[0] = pk2bf(__builtin_amdgcn_exp2f(s0[0]), __builtin_amdgcn_exp2f(s0[1]));
                pa.w[1] = pk2bf(__builtin_amdgcn_exp2f(s0[2]), __builtin_amdgcn_exp2f(s0[3]));
                pa.w[2] = pk2bf(__builtin_amdgcn_exp2f(s1[0]), __builtin_amdgcn_exp2f(s1[1]));
                pa.w[3] = pk2bf(__builtin_amdgcn_exp2f(s1[2]), __builtin_amdgcn_exp2f(s1[3]));
                oB0 = __builtin_amdgcn_mfma_f32_16x16x32_bf16(pa.v, vb0, oB0, 0, 0, 0);
                oB1 = __builtin_amdgcn_mfma_f32_16x16x32_bf16(pa.v, vb1, oB1, 0, 0, 0);
                lB  = __builtin_amdgcn_mfma_f32_16x16x32_bf16(pa.v, ones, lB, 0, 0, 0);
            }
        }
        #pragma unroll
        for (int half = 0; half < 2; ++half) {
            const f32x4 o0 = half ? oB0 : oA0;
            const f32x4 o1 = half ? oB1 : oA1;
            const f32x4 lc = half ? lB : lA;
            const int q0 = half ? q0b : q0a;
            #pragma unroll
            for (int r = 0; r < 4; ++r) {
                const float inv = 1.0f / lc[r];
                Os[wave][g * 4 + r][cl]      = f2bf(o0[r] * inv);
                Os[wave][g * 4 + r][16 + cl] = f2bf(o1[r] * inv);
            }
            const int row = lane >> 2, cg = (lane & 3) * 8;
            const int q = q0 + row;
            if (q < NTOK)
                *(float4*)(opb + (rowbase + q) * CDIM + h * HD + cg) =
                    *(const float4*)&Os[wave][row][cg];
        }
    }
}

// ---------------------------------------------------------------- proj GEMM
// R9 version (kept): single opb read — 64-row tile staged once, loop both
// 96-col f-chunks in-block. One-pass epilogue (waves write disjoint Cf
// regions). LDS 52,224B -> 3 blocks/CU.
__global__ __launch_bounds__(256, 3) void gemm_proj(
    const u16* __restrict__ opb, const u16* __restrict__ wpb,
    const float* __restrict__ bp, float* __restrict__ out)
{
    __shared__ __align__(16) u16 Xs[64 * 200];        // live whole kernel
    __shared__ __align__(16) float Cf[64 * 104];      // epilogue transpose (f32)
    const int m0 = blockIdx.x * 64;
    const int tid = threadIdx.x;
    const int wave = tid >> 6, lane = tid & 63, g = lane >> 4, cl = lane & 15;
    const int wm = (wave >> 1) * 32, wf = (wave & 1) * 48;

    // stage once: 64 rows x 24 float4 units = 1536 (6 passes of 256)
    #pragma unroll
    for (int p = 0; p < 6; ++p) {
        const int u = tid + 256 * p;
        const int row = u / 24, c = u - row * 24;
        *(float4*)(Xs + row * 200 + c * 8) =
            *(const float4*)(opb + (size_t)(m0 + row) * CDIM + c * 8);
    }
    __syncthreads();

    for (int fc = 0; fc < 2; ++fc) {
        const int f0 = fc * 96;
        f32x4 acc[2][3];
        #pragma unroll
        for (int t = 0; t < 2; ++t)
            #pragma unroll
            for (int s = 0; s < 3; ++s) acc[t][s] = (f32x4){0.f, 0.f, 0.f, 0.f};

        const u16* wbase = wpb + (size_t)(fc * 6 + (wave & 1) * 3) * 3072 + lane * 8;
        #pragma unroll
        for (int kk = 0; kk < 6; ++kk) {
            const int kcol = kk * 32;
            bf16x8 a[2], bb[3];
            #pragma unroll
            for (int s = 0; s < 3; ++s)
                bb[s] = *(const bf16x8*)(wbase + s * 3072 + kk * 512);
            #pragma unroll
            for (int t = 0; t < 2; ++t)
                a[t] = *(const bf16x8*)(Xs + (wm + t * 16 + cl) * 200 + kcol + g * 8);
            #pragma unroll
            for (int t = 0; t < 2; ++t)
                #pragma unroll
                for (int s = 0; s < 3; ++s)
                    acc[t][s] = __builtin_amdgcn_mfma_f32_16x16x32_bf16(a[t], bb[s], acc[t][s], 0, 0, 0);
        }

        __syncthreads();                              // prev fc's Cf reads done
        #pragma unroll
        for (int s = 0; s < 3; ++s) {
            const float bv = bp[f0 + wf + s * 16 + cl];
            #pragma unroll
            for (int t = 0; t < 2; ++t)
                #pragma unroll
                for (int r = 0; r < 4; ++r)
                    Cf[(wm + t * 16 + g * 4 + r) * 104 + wf + s * 16 + cl] = acc[t][s][r] + bv;
        }
        __syncthreads();
        #pragma unroll
        for (int p = 0; p < 6; ++p) {                 // coalesced 16B stores
            const int u = tid + 256 * p;
            const int row = u / 24, c = u - row * 24;
            *(float4*)(out + (size_t)(m0 + row) * CDIM + f0 + c * 4) =
                *(const float4*)(Cf + row * 104 + c * 4);
        }
    }
}

// ---------------------------------------------------------------- launch
extern "C" void kernel_launch(void* const* d_in, const int* in_sizes, int n_in,
                              void* d_out, int out_size, void* d_ws, size_t ws_size,
                              hipStream_t stream) {
    const float* x     = (const float*)d_in[0];
    const float* wqkv  = (const float*)d_in[1];
    const float* bqkv  = (const float*)d_in[2];
    const float* wproj = (const float*)d_in[3];
    const float* bproj = (const float*)d_in[4];
    const float* btab  = (const float*)d_in[5];
    const int*   ridx  = (const int*)d_in[6];
    float* out = (float*)d_out;

    if (ws_size < WS_NEED) {
        hipLaunchKernelGGL(ws_too_small_sentinel, dim3(1), dim3(1), 0, stream, out);
        return;
    }
    char* ws = (char*)d_ws;
    u16*   qkvb = (u16*)(ws + OFF_QKVB);
    u16*   wqb  = (u16*)(ws + OFF_WQB);
    u16*   wpb  = (u16*)(ws + OFF_WPB);
    float* bqs  = (float*)(ws + OFF_BQS);
    u16*   bmb  = (u16*)(ws + OFF_BMB);
    u16*   opb  = (u16*)(ws + OFF_OPB);

    hipLaunchKernelGGL(cvt_small, dim3(3483), dim3(256), 0, stream,
                       wqkv, wproj, bqkv, btab, ridx, wqb, wpb, bqs, bmb);
    hipLaunchKernelGGL(gemm_qkv, dim3(NROWS / 64), dim3(256), 0, stream,
                       x, wqb, bqs, qkvb);
    hipLaunchKernelGGL(attn_mfma, dim3(BWIN, NH), dim3(256), 0, stream,
                       qkvb, bmb, opb);
    hipLaunchKernelGGL(gemm_proj, dim3(NROWS / 64), dim3(256), 0, stream,
                       opb, wpb, bproj, out);
}